// Round 7
// baseline (388.445 us; speedup 1.0000x reference)
//
#include <hip/hip_runtime.h>
#include <stdint.h>

// AAM-Softmax fused: loss + acc for B=1024, C=100000, D=256.
//   k_norm8f: L2-normalize rows fp32 -> fp8 e4m3 in pair-interleaved MFMA
//       fragment layout (B-tile = 4 KB contiguous; wave reads it as
//       4 x dwordx4 = 1 KB/instr).
//   k_target: per-row target cos from fp32 originals (exact for the -30*tl
//       loss term) + adjusted/unadjusted target p for the S correction.
//   k_main: rows OUTER (A-frags + per-row sum/max in registers), classes
//       INNER streaming L2-resident fp8 B. Hot loop: 4 VALU ops/logit, no
//       branches. R6 lessons: harness fills (400 MB d_ws poison ~60us) are
//       ~half the measured time; k_main <59us is latency-limited at 6
//       blocks/CU. R7: launch_bounds(256,8) -> all 2048 blocks co-resident
//       (32 waves/CU) + explicit B double-buffer so the ~200cyc L2 load
//       latency overlaps the MFMA chain instead of serializing per tile.
//   k_final: reduce 256 partials/row, S' = S - p_u + p_adj, loss/acc, mean.
#define DIM    256
#define BATCH  1024
#define NCLS   100000
#define NCT    256                     // class groups
#define TPG    25                      // 16-class tiles per group
#define CPG    (TPG * 16)              // 400 classes per group
#define NCLS_PAD (NCT * CPG)           // 102400; pads zero -> p=2^-43 each
#define RG     8                       // row groups
#define CLIPV  0.9999999f              // 1 - 1e-7 (matches ref fp32 clip)
#define COSM   0.98006657784124163f    // cos(0.2)
#define SINM   0.19866933079506122f    // sin(0.2)
#define K30L2E 43.280851226668903f     // 30 * log2(e)

typedef __attribute__((ext_vector_type(4))) float floatx4;
typedef __attribute__((ext_vector_type(2))) unsigned long ulong2v;  // 16 B

// ws layout (~28.6 MB)
#define EMBF_OFF 0                                     // 256 KB fp8 emb frags
#define WGTF_OFF (256 * 1024)                          // 25.6 MB fp8 wgt frags
#define TL_OFF   (WGTF_OFF + (size_t)NCLS_PAD * DIM)   // 4 KB adj target cos
#define PU_OFF   (TL_OFF + 4096)                       // 4 KB unadj target p
#define SP_OFF   (PU_OFF + 4096)                       // 256x1024 f32 partials
#define MP_OFF   (SP_OFF + (size_t)NCT * BATCH * 4)    // 256x1024 u32 partials

// ---- k_norm8f: L2-normalize -> fp8 e4m3, pair-interleaved fragment layout --
// Layout: byte (row, k) -> tile(row>>4)*4096 + (s>>1)*1024 + lane*16 +
// (s&1)*8 + (k&7), where s=k>>5, lane=(row&15)+16*((k>>3)&3).
// 16 rows (1 tile) per block; rows >= nvalid write zeros (pad classes).
__global__ __launch_bounds__(256) void k_norm8f(
        const float* __restrict__ src, unsigned char* __restrict__ dst,
        int nvalid) {
    const int tid = threadIdx.x;
    const int w = tid >> 6, l = tid & 63;
    const int r   = blockIdx.x * 16 + w * 4 + (l >> 4);  // global row
    const int r16 = r & 15;
    const int l16 = l & 15;                       // 16 floats per lane
    float v[16];
    float ss = 0.f;
    if (r < nvalid) {
        const float* rp = src + (size_t)r * DIM + l16 * 16;
#pragma unroll
        for (int i = 0; i < 4; ++i) {
            float4 a = *(const float4*)(rp + i * 4);
            v[i*4+0]=a.x; v[i*4+1]=a.y; v[i*4+2]=a.z; v[i*4+3]=a.w;
            ss += a.x*a.x + a.y*a.y + a.z*a.z + a.w*a.w;
        }
    } else {
#pragma unroll
        for (int i = 0; i < 16; ++i) v[i] = 0.f;
    }
#pragma unroll
    for (int k = 1; k < 16; k <<= 1) ss += __shfl_xor(ss, k);
    const float sc = 1.f / fmaxf(sqrtf(ss), 1e-12f);
    unsigned char* tb = dst + (size_t)(r >> 4) * 4096;
#pragma unroll
    for (int h = 0; h < 2; ++h) {             // two 8-byte k-groups per lane
        const int g = 2 * l16 + h;            // k = 8g..8g+7
        const int s = g >> 2, q = g & 3;
        int p0 = 0, p1 = 0;
        p0 = __builtin_amdgcn_cvt_pk_fp8_f32(v[h*8+0]*sc, v[h*8+1]*sc, p0, false);
        p0 = __builtin_amdgcn_cvt_pk_fp8_f32(v[h*8+2]*sc, v[h*8+3]*sc, p0, true);
        p1 = __builtin_amdgcn_cvt_pk_fp8_f32(v[h*8+4]*sc, v[h*8+5]*sc, p1, false);
        p1 = __builtin_amdgcn_cvt_pk_fp8_f32(v[h*8+6]*sc, v[h*8+7]*sc, p1, true);
        uint2 o; o.x = (unsigned)p0; o.y = (unsigned)p1;
        *(uint2*)(tb + (s >> 1) * 1024 + (r16 + 16 * q) * 16 + (s & 1) * 8) = o;
    }
}

// ---- k_target: per-row target cos (fp32) + adjusted/unadjusted p ----------
__global__ __launch_bounds__(256) void k_target(
        const float* __restrict__ emb, const float* __restrict__ wgt,
        const int* __restrict__ labels,
        float* __restrict__ TL, float* __restrict__ PU) {
    const int tid = threadIdx.x;
    const int w = tid >> 6, l = tid & 63;
    const int r   = blockIdx.x * 16 + w * 4 + (l >> 4);
    const int l16 = l & 15;
    const int lbl = labels[r];
    const float* ep = emb + (size_t)r * DIM + l16 * 16;
    const float* wp = wgt + (size_t)lbl * DIM + l16 * 16;
    float de = 0.f, dw = 0.f, dd = 0.f;
#pragma unroll
    for (int i = 0; i < 4; ++i) {
        float4 a = *(const float4*)(ep + i * 4);
        float4 b = *(const float4*)(wp + i * 4);
        de += a.x*a.x + a.y*a.y + a.z*a.z + a.w*a.w;
        dw += b.x*b.x + b.y*b.y + b.z*b.z + b.w*b.w;
        dd += a.x*b.x + a.y*b.y + a.z*b.z + a.w*b.w;
    }
#pragma unroll
    for (int k = 1; k < 16; k <<= 1) {
        de += __shfl_xor(de, k); dw += __shfl_xor(dw, k); dd += __shfl_xor(dd, k);
    }
    if (l16 == 0) {
        float t = dd / (fmaxf(sqrtf(de), 1e-12f) * fmaxf(sqrtf(dw), 1e-12f));
        t = fminf(fmaxf(t, -CLIPV), CLIPV);
        PU[r] = exp2f(fmaf(t, K30L2E, -K30L2E));          // unadjusted p
        TL[r] = t * COSM - sqrtf(fmaxf(1.f - t * t, 0.f)) * SINM;  // margin
    }
}

// ---------------- k_main: fused GEMM + register softmax partials ----------
__global__ __launch_bounds__(256, 8) void k_main(
        const unsigned char* __restrict__ wgt8f,
        const unsigned char* __restrict__ emb8f,
        float* __restrict__ SP, unsigned* __restrict__ MP) {
    const int cg = blockIdx.x;            // class group -> XCD cg%8 local
    const int rg = blockIdx.y;            // row group
    const int tid = threadIdx.x;
    const int w = tid >> 6, l = tid & 63;
    const int r16 = l & 15, q = l >> 4;
    const int rowbase = rg * 128 + w * 32;   // wave's 32 rows (2 M-tiles)

    // A-fragments held in registers the whole kernel (fragment layout)
    long af[2][8];
#pragma unroll
    for (int mt = 0; mt < 2; ++mt) {
        const ulong2v* ap =
            (const ulong2v*)(emb8f + (size_t)((rowbase >> 4) + mt) * 4096) + l;
#pragma unroll
        for (int p = 0; p < 4; ++p) {
            ulong2v v = ap[p * 64];
            af[mt][2*p]   = (long)v.x;
            af[mt][2*p+1] = (long)v.y;
        }
    }

    float sum[2][4] = {{0.f,0.f,0.f,0.f},{0.f,0.f,0.f,0.f}};
    float mx [2][4] = {{0.f,0.f,0.f,0.f},{0.f,0.f,0.f,0.f}};  // max of p

    const ulong2v* bp = (const ulong2v*)(wgt8f + (size_t)(cg * TPG) * 4096) + l;
    // double-buffered B: tile t+1's loads issue before tile t's compute
    ulong2v v0 = bp[0], v1 = bp[64], v2 = bp[128], v3 = bp[192];
    for (int t = 0; t < TPG; ++t) {
        long bf[8];
        bf[0] = (long)v0.x; bf[1] = (long)v0.y;
        bf[2] = (long)v1.x; bf[3] = (long)v1.y;
        bf[4] = (long)v2.x; bf[5] = (long)v2.y;
        bf[6] = (long)v3.x; bf[7] = (long)v3.y;
        if (t + 1 < TPG) {                        // prefetch next tile
            bp += 256;
            v0 = bp[0]; v1 = bp[64]; v2 = bp[128]; v3 = bp[192];
        }
#pragma unroll
        for (int mt = 0; mt < 2; ++mt) {
            floatx4 acc = {0.f, 0.f, 0.f, 0.f};
#pragma unroll
            for (int s = 0; s < 8; ++s)
                acc = __builtin_amdgcn_mfma_f32_16x16x32_fp8_fp8(af[mt][s], bf[s], acc, 0, 0, 0);
            // 4 ops/logit: fma, exp2, add, max — nothing else (no clip:
            // |cos| < ~0.35 for this data; target handled in k_target)
#pragma unroll
            for (int r = 0; r < 4; ++r) {
                const float p = exp2f(fmaf(acc[r], K30L2E, -K30L2E));
                sum[mt][r] += p;
                mx[mt][r] = fmaxf(mx[mt][r], p);
            }
        }
    }

    // one butterfly per wave (over the 16 class-columns)
#pragma unroll
    for (int k = 1; k < 16; k <<= 1)
#pragma unroll
        for (int mt = 0; mt < 2; ++mt)
#pragma unroll
            for (int r = 0; r < 4; ++r) {
                sum[mt][r] += __shfl_xor(sum[mt][r], k);
                mx[mt][r] = fmaxf(mx[mt][r], __shfl_xor(mx[mt][r], k));
            }
    if (r16 < 4) {
#pragma unroll
        for (int mt = 0; mt < 2; ++mt) {
            float sv = sum[mt][0], mv = mx[mt][0];
            if (r16 == 1) { sv = sum[mt][1]; mv = mx[mt][1]; }
            else if (r16 == 2) { sv = sum[mt][2]; mv = mx[mt][2]; }
            else if (r16 == 3) { sv = sum[mt][3]; mv = mx[mt][3]; }
            const int row = rowbase + mt * 16 + q * 4 + r16;
            SP[cg * BATCH + row] = sv;
            MP[cg * BATCH + row] = __float_as_uint(mv);
        }
    }
}

// ---------------- k_final: reduce partials + loss/acc + mean -------------
__global__ __launch_bounds__(256) void k_final(
        const float* __restrict__ SP, const unsigned* __restrict__ MP,
        const float* __restrict__ TL, const float* __restrict__ PU,
        float* __restrict__ out) {
    __shared__ float    ls[16][16];
    __shared__ unsigned lm[16][16];
    const int tid = threadIdx.x;
    const int r16 = tid & 15;                 // row within block
    const int c   = tid >> 4;                 // partial-chunk lane
    const int row = blockIdx.x * 16 + r16;
    float s = 0.f;
    unsigned m = 0u;
    for (int b = c; b < NCT; b += 16) {       // 16 iters, 64B-coalesced
        s += SP[(size_t)b * BATCH + row];
        const unsigned v = MP[(size_t)b * BATCH + row];
        m = v > m ? v : m;
    }
    ls[c][r16] = s; lm[c][r16] = m;
    __syncthreads();
    float loss = 0.f, corr = 0.f;
    if (tid < 16) {
        float st = 0.f; unsigned mt = 0u;
#pragma unroll
        for (int i = 0; i < 16; ++i) {
            st += ls[i][tid];
            mt = lm[i][tid] > mt ? lm[i][tid] : mt;
        }
        const int r = blockIdx.x * 16 + tid;
        const float tl = TL[r];
        const float padj = exp2f(fmaf(tl, K30L2E, -K30L2E));
        st = st - PU[r] + padj;               // swap target p: unadj -> adj
        loss = 30.f + logf(st) - 30.f * tl;   // logsumexp - target logit
        corr = (padj >= __uint_as_float(mt)) ? 1.f : 0.f;
    }
#pragma unroll
    for (int k = 1; k < 16; k <<= 1) {        // lanes 16..63 carry zeros
        loss += __shfl_xor(loss, k);
        corr += __shfl_xor(corr, k);
    }
    if (tid == 0) {
        atomicAdd(out + 0, loss * (1.f / 1024.f));
        atomicAdd(out + 1, corr * (1.f / 1024.f));
    }
}

extern "C" void kernel_launch(void* const* d_in, const int* in_sizes, int n_in,
                              void* d_out, int out_size, void* d_ws, size_t ws_size,
                              hipStream_t stream) {
    (void)in_sizes; (void)n_in; (void)out_size; (void)ws_size;
    const float* emb    = (const float*)d_in[0];
    const float* wgt    = (const float*)d_in[1];
    const int*   labels = (const int*)d_in[2];
    char* ws = (char*)d_ws;
    unsigned char* emb8f = (unsigned char*)(ws + EMBF_OFF);
    unsigned char* wgt8f = (unsigned char*)(ws + WGTF_OFF);
    float*    TL = (float*)(ws + TL_OFF);
    float*    PU = (float*)(ws + PU_OFF);
    float*    SP = (float*)(ws + SP_OFF);
    unsigned* MP = (unsigned*)(ws + MP_OFF);

    hipMemsetAsync(d_out, 0, 2 * sizeof(float), stream);  // k_final accumulates
    k_norm8f<<<BATCH / 16, 256, 0, stream>>>(emb, emb8f, BATCH);
    k_norm8f<<<NCLS_PAD / 16, 256, 0, stream>>>(wgt, wgt8f, NCLS);
    k_target<<<BATCH / 16, 256, 0, stream>>>(emb, wgt, labels, TL, PU);
    k_main<<<dim3(NCT, RG), 256, 0, stream>>>(wgt8f, emb8f, SP, MP);
    k_final<<<64, 256, 0, stream>>>(SP, MP, TL, PU, (float*)d_out);
}

// Round 8
// 224.178 us; speedup vs baseline: 1.7328x; 1.7328x over previous
//
#include <hip/hip_runtime.h>
#include <stdint.h>

// AAM-Softmax fused: loss + acc for B=1024, C=100000, D=256.
//   k_norm8f: L2-normalize rows fp32 -> fp8 e4m3 in pair-interleaved MFMA
//       fragment layout (B-tile = 4 KB contiguous; wave reads it as
//       4 x dwordx4 = 1 KB/instr).
//   k_target: per-row target cos from fp32 originals (exact for the -30*tl
//       loss term) + adjusted/unadjusted target p for the S correction.
//   k_main: rows OUTER (A-frags + per-row sum/max in registers), classes
//       INNER streaming L2-resident fp8 B with an explicit double-buffer.
//       R7 lesson: launch_bounds(256,8) forced 64-VGPR cap -> scratch spill
//       (FETCH 567 MB, WRITE 364 MB, 230 us). R8: 16 rows/wave halves the
//       A-frag + accumulator footprint (~75 VGPR) so prefetch fits under
//       the bounds(256,6) 85-VGPR cap with zero spill. B traffic doubles
//       to 410 MB but is per-XCD L2-local (3.2 MB working set, ~12 us).
//   k_final: reduce 256 partials/row, S' = S - p_u + p_adj, loss/acc, mean.
#define DIM    256
#define BATCH  1024
#define NCLS   100000
#define NCT    256                     // class groups
#define TPG    25                      // 16-class tiles per group
#define CPG    (TPG * 16)              // 400 classes per group
#define NCLS_PAD (NCT * CPG)           // 102400; pads zero -> p=2^-43 each
#define RG     16                      // row groups (64 rows per block)
#define CLIPV  0.9999999f              // 1 - 1e-7 (matches ref fp32 clip)
#define COSM   0.98006657784124163f    // cos(0.2)
#define SINM   0.19866933079506122f    // sin(0.2)
#define K30L2E 43.280851226668903f     // 30 * log2(e)

typedef __attribute__((ext_vector_type(4))) float floatx4;
typedef __attribute__((ext_vector_type(2))) unsigned long ulong2v;  // 16 B

// ws layout (~28.6 MB)
#define EMBF_OFF 0                                     // 256 KB fp8 emb frags
#define WGTF_OFF (256 * 1024)                          // 25.6 MB fp8 wgt frags
#define TL_OFF   (WGTF_OFF + (size_t)NCLS_PAD * DIM)   // 4 KB adj target cos
#define PU_OFF   (TL_OFF + 4096)                       // 4 KB unadj target p
#define SP_OFF   (PU_OFF + 4096)                       // 256x1024 f32 partials
#define MP_OFF   (SP_OFF + (size_t)NCT * BATCH * 4)    // 256x1024 u32 partials

// ---- k_norm8f: L2-normalize -> fp8 e4m3, pair-interleaved fragment layout --
// Layout: byte (row, k) -> tile(row>>4)*4096 + (s>>1)*1024 + lane*16 +
// (s&1)*8 + (k&7), where s=k>>5, lane=(row&15)+16*((k>>3)&3).
// 16 rows (1 tile) per block; rows >= nvalid write zeros (pad classes).
__global__ __launch_bounds__(256) void k_norm8f(
        const float* __restrict__ src, unsigned char* __restrict__ dst,
        int nvalid) {
    const int tid = threadIdx.x;
    const int w = tid >> 6, l = tid & 63;
    const int r   = blockIdx.x * 16 + w * 4 + (l >> 4);  // global row
    const int r16 = r & 15;
    const int l16 = l & 15;                       // 16 floats per lane
    float v[16];
    float ss = 0.f;
    if (r < nvalid) {
        const float* rp = src + (size_t)r * DIM + l16 * 16;
#pragma unroll
        for (int i = 0; i < 4; ++i) {
            float4 a = *(const float4*)(rp + i * 4);
            v[i*4+0]=a.x; v[i*4+1]=a.y; v[i*4+2]=a.z; v[i*4+3]=a.w;
            ss += a.x*a.x + a.y*a.y + a.z*a.z + a.w*a.w;
        }
    } else {
#pragma unroll
        for (int i = 0; i < 16; ++i) v[i] = 0.f;
    }
#pragma unroll
    for (int k = 1; k < 16; k <<= 1) ss += __shfl_xor(ss, k);
    const float sc = 1.f / fmaxf(sqrtf(ss), 1e-12f);
    unsigned char* tb = dst + (size_t)(r >> 4) * 4096;
#pragma unroll
    for (int h = 0; h < 2; ++h) {             // two 8-byte k-groups per lane
        const int g = 2 * l16 + h;            // k = 8g..8g+7
        const int s = g >> 2, q = g & 3;
        int p0 = 0, p1 = 0;
        p0 = __builtin_amdgcn_cvt_pk_fp8_f32(v[h*8+0]*sc, v[h*8+1]*sc, p0, false);
        p0 = __builtin_amdgcn_cvt_pk_fp8_f32(v[h*8+2]*sc, v[h*8+3]*sc, p0, true);
        p1 = __builtin_amdgcn_cvt_pk_fp8_f32(v[h*8+4]*sc, v[h*8+5]*sc, p1, false);
        p1 = __builtin_amdgcn_cvt_pk_fp8_f32(v[h*8+6]*sc, v[h*8+7]*sc, p1, true);
        uint2 o; o.x = (unsigned)p0; o.y = (unsigned)p1;
        *(uint2*)(tb + (s >> 1) * 1024 + (r16 + 16 * q) * 16 + (s & 1) * 8) = o;
    }
}

// ---- k_target: per-row target cos (fp32) + adjusted/unadjusted p ----------
__global__ __launch_bounds__(256) void k_target(
        const float* __restrict__ emb, const float* __restrict__ wgt,
        const int* __restrict__ labels,
        float* __restrict__ TL, float* __restrict__ PU) {
    const int tid = threadIdx.x;
    const int w = tid >> 6, l = tid & 63;
    const int r   = blockIdx.x * 16 + w * 4 + (l >> 4);
    const int l16 = l & 15;
    const int lbl = labels[r];
    const float* ep = emb + (size_t)r * DIM + l16 * 16;
    const float* wp = wgt + (size_t)lbl * DIM + l16 * 16;
    float de = 0.f, dw = 0.f, dd = 0.f;
#pragma unroll
    for (int i = 0; i < 4; ++i) {
        float4 a = *(const float4*)(ep + i * 4);
        float4 b = *(const float4*)(wp + i * 4);
        de += a.x*a.x + a.y*a.y + a.z*a.z + a.w*a.w;
        dw += b.x*b.x + b.y*b.y + b.z*b.z + b.w*b.w;
        dd += a.x*b.x + a.y*b.y + a.z*b.z + a.w*b.w;
    }
#pragma unroll
    for (int k = 1; k < 16; k <<= 1) {
        de += __shfl_xor(de, k); dw += __shfl_xor(dw, k); dd += __shfl_xor(dd, k);
    }
    if (l16 == 0) {
        float t = dd / (fmaxf(sqrtf(de), 1e-12f) * fmaxf(sqrtf(dw), 1e-12f));
        t = fminf(fmaxf(t, -CLIPV), CLIPV);
        PU[r] = exp2f(fmaf(t, K30L2E, -K30L2E));          // unadjusted p
        TL[r] = t * COSM - sqrtf(fmaxf(1.f - t * t, 0.f)) * SINM;  // margin
    }
}

// ---------------- k_main: fused GEMM + register softmax partials ----------
__global__ __launch_bounds__(256, 6) void k_main(
        const unsigned char* __restrict__ wgt8f,
        const unsigned char* __restrict__ emb8f,
        float* __restrict__ SP, unsigned* __restrict__ MP) {
    const int cg = blockIdx.x;            // class group -> XCD cg%8 local
    const int rg = blockIdx.y;            // row group
    const int tid = threadIdx.x;
    const int w = tid >> 6, l = tid & 63;
    const int r16 = l & 15, q = l >> 4;
    const int rowbase = rg * 64 + w * 16;    // wave's 16 rows (1 M-tile)

    // A-fragments held in registers the whole kernel (fragment layout)
    long af[8];
    {
        const ulong2v* ap =
            (const ulong2v*)(emb8f + (size_t)(rowbase >> 4) * 4096) + l;
#pragma unroll
        for (int p = 0; p < 4; ++p) {
            ulong2v v = ap[p * 64];
            af[2*p]   = (long)v.x;
            af[2*p+1] = (long)v.y;
        }
    }

    float sum[4] = {0.f, 0.f, 0.f, 0.f};
    float mx [4] = {0.f, 0.f, 0.f, 0.f};   // max of p (monotone in logit)

    const ulong2v* bp = (const ulong2v*)(wgt8f + (size_t)(cg * TPG) * 4096) + l;
    // double-buffered B: tile t+1's loads issue before tile t's compute
    ulong2v v0 = bp[0], v1 = bp[64], v2 = bp[128], v3 = bp[192];
    for (int t = 0; t < TPG; ++t) {
        long bf[8];
        bf[0] = (long)v0.x; bf[1] = (long)v0.y;
        bf[2] = (long)v1.x; bf[3] = (long)v1.y;
        bf[4] = (long)v2.x; bf[5] = (long)v2.y;
        bf[6] = (long)v3.x; bf[7] = (long)v3.y;
        if (t + 1 < TPG) {                        // prefetch next tile
            bp += 256;
            v0 = bp[0]; v1 = bp[64]; v2 = bp[128]; v3 = bp[192];
        }
        floatx4 acc = {0.f, 0.f, 0.f, 0.f};
#pragma unroll
        for (int s = 0; s < 8; ++s)
            acc = __builtin_amdgcn_mfma_f32_16x16x32_fp8_fp8(af[s], bf[s], acc, 0, 0, 0);
        // 4 ops/logit: fma, exp2, add, max — nothing else (no clip:
        // |cos| < ~0.35 for this data; target handled in k_target)
#pragma unroll
        for (int r = 0; r < 4; ++r) {
            const float p = exp2f(fmaf(acc[r], K30L2E, -K30L2E));
            sum[r] += p;
            mx[r] = fmaxf(mx[r], p);
        }
    }

    // one butterfly per wave (over the 16 class-columns)
#pragma unroll
    for (int k = 1; k < 16; k <<= 1)
#pragma unroll
        for (int r = 0; r < 4; ++r) {
            sum[r] += __shfl_xor(sum[r], k);
            mx[r] = fmaxf(mx[r], __shfl_xor(mx[r], k));
        }
    if (r16 < 4) {
        float sv = sum[0], mv = mx[0];
        if (r16 == 1) { sv = sum[1]; mv = mx[1]; }
        else if (r16 == 2) { sv = sum[2]; mv = mx[2]; }
        else if (r16 == 3) { sv = sum[3]; mv = mx[3]; }
        const int row = rowbase + q * 4 + r16;
        SP[cg * BATCH + row] = sv;
        MP[cg * BATCH + row] = __float_as_uint(mv);
    }
}

// ---------------- k_final: reduce partials + loss/acc + mean -------------
__global__ __launch_bounds__(256) void k_final(
        const float* __restrict__ SP, const unsigned* __restrict__ MP,
        const float* __restrict__ TL, const float* __restrict__ PU,
        float* __restrict__ out) {
    __shared__ float    ls[16][16];
    __shared__ unsigned lm[16][16];
    const int tid = threadIdx.x;
    const int r16 = tid & 15;                 // row within block
    const int c   = tid >> 4;                 // partial-chunk lane
    const int row = blockIdx.x * 16 + r16;
    float s = 0.f;
    unsigned m = 0u;
    for (int b = c; b < NCT; b += 16) {       // 16 iters, 64B-coalesced
        s += SP[(size_t)b * BATCH + row];
        const unsigned v = MP[(size_t)b * BATCH + row];
        m = v > m ? v : m;
    }
    ls[c][r16] = s; lm[c][r16] = m;
    __syncthreads();
    float loss = 0.f, corr = 0.f;
    if (tid < 16) {
        float st = 0.f; unsigned mt = 0u;
#pragma unroll
        for (int i = 0; i < 16; ++i) {
            st += ls[i][tid];
            mt = lm[i][tid] > mt ? lm[i][tid] : mt;
        }
        const int r = blockIdx.x * 16 + tid;
        const float tl = TL[r];
        const float padj = exp2f(fmaf(tl, K30L2E, -K30L2E));
        st = st - PU[r] + padj;               // swap target p: unadj -> adj
        loss = 30.f + logf(st) - 30.f * tl;   // logsumexp - target logit
        corr = (padj >= __uint_as_float(mt)) ? 1.f : 0.f;
    }
#pragma unroll
    for (int k = 1; k < 16; k <<= 1) {        // lanes 16..63 carry zeros
        loss += __shfl_xor(loss, k);
        corr += __shfl_xor(corr, k);
    }
    if (tid == 0) {
        atomicAdd(out + 0, loss * (1.f / 1024.f));
        atomicAdd(out + 1, corr * (1.f / 1024.f));
    }
}

extern "C" void kernel_launch(void* const* d_in, const int* in_sizes, int n_in,
                              void* d_out, int out_size, void* d_ws, size_t ws_size,
                              hipStream_t stream) {
    (void)in_sizes; (void)n_in; (void)out_size; (void)ws_size;
    const float* emb    = (const float*)d_in[0];
    const float* wgt    = (const float*)d_in[1];
    const int*   labels = (const int*)d_in[2];
    char* ws = (char*)d_ws;
    unsigned char* emb8f = (unsigned char*)(ws + EMBF_OFF);
    unsigned char* wgt8f = (unsigned char*)(ws + WGTF_OFF);
    float*    TL = (float*)(ws + TL_OFF);
    float*    PU = (float*)(ws + PU_OFF);
    float*    SP = (float*)(ws + SP_OFF);
    unsigned* MP = (unsigned*)(ws + MP_OFF);

    hipMemsetAsync(d_out, 0, 2 * sizeof(float), stream);  // k_final accumulates
    k_norm8f<<<BATCH / 16, 256, 0, stream>>>(emb, emb8f, BATCH);
    k_norm8f<<<NCLS_PAD / 16, 256, 0, stream>>>(wgt, wgt8f, NCLS);
    k_target<<<BATCH / 16, 256, 0, stream>>>(emb, wgt, labels, TL, PU);
    k_main<<<dim3(NCT, RG), 256, 0, stream>>>(wgt8f, emb8f, SP, MP);
    k_final<<<64, 256, 0, stream>>>(SP, MP, TL, PU, (float*)d_out);
}

// Round 9
// 218.250 us; speedup vs baseline: 1.7798x; 1.0272x over previous
//
#include <hip/hip_runtime.h>
#include <stdint.h>

// AAM-Softmax fused: loss + acc for B=1024, C=100000, D=256.
//   k_prep (single launch, 3 grid segments):
//     [0,64):      L2-normalize emb rows -> fp8 e4m3 fragment layout
//     [64,6314):   L2-normalize wgt rows -> fp8 e4m3 fragment layout
//     [6314,6378): per-row target cos in fp32 (exact loss term) + p_u
//   Inputs are scaled by sqrt(30*log2e) so the fp8 MFMA emits
//   acc = 30*log2e*cos directly -> hot-loop epilogue is 3 ops/logit
//   (exp2, add, max) in the UNSHIFTED domain (max exp = e^30 = 1e13, fp32-safe).
//   k_main: rows OUTER (A-frags + per-row sum/max registers), classes INNER
//     streaming L2-resident fp8 B. 2 M-tiles/wave (R8 lesson: 1 M-tile
//     doubled per-logit overhead, 64.7us vs R6's <59; R7 lesson: explicit
//     prefetch doesn't fit the 85-VGPR cap -> spill). NCT=250: 100000 =
//     250 x 400 exactly, no pad classes, no pad bias.
//   k_final: reduce 250 partials/row, S' = S - p_u + p_adj,
//     loss = log(S') - 30*tl, acc via max compare, mean.
#define DIM    256
#define BATCH  1024
#define NCLS   100000
#define NCT    250                     // class groups (exact: 250*400=100000)
#define TPG    25                      // 16-class tiles per group
#define CPG    400                     // classes per group
#define RG     8                       // row groups (128 rows per block)
#define WGTBLK 6250                    // weight tiles (100000/16)
#define CLIPV  0.9999999f              // 1 - 1e-7 (matches ref fp32 clip)
#define COSM   0.98006657784124163f    // cos(0.2)
#define SINM   0.19866933079506122f    // sin(0.2)
#define K30L2E 43.280851226668903f     // 30 * log2(e)
#define SQK    6.5788184f              // sqrt(30*log2(e)) input pre-scale

typedef __attribute__((ext_vector_type(4))) float floatx4;
typedef __attribute__((ext_vector_type(2))) unsigned long ulong2v;  // 16 B

// ws layout (~27.9 MB)
#define EMBF_OFF 0                                   // 256 KB fp8 emb frags
#define WGTF_OFF (256 * 1024)                        // 25.6 MB fp8 wgt frags
#define TL_OFF   (WGTF_OFF + (size_t)NCLS * DIM)     // 4 KB adj target cos
#define PU_OFF   (TL_OFF + 4096)                     // 4 KB unadj target p
#define SP_OFF   (PU_OFF + 4096)                     // 250x1024 f32 partials
#define MP_OFF   (SP_OFF + (size_t)NCT * BATCH * 4)  // 250x1024 u32 partials

// ---- k_prep: one launch, three segments ----------------------------------
// Fragment layout: byte (row,k) -> tile(row>>4)*4096 + (s>>1)*1024 + lane*16
// + (s&1)*8 + (k&7), s=k>>5, lane=(row&15)+16*((k>>3)&3).
__global__ __launch_bounds__(256) void k_prep(
        const float* __restrict__ emb, const float* __restrict__ wgt,
        const int* __restrict__ labels,
        unsigned char* __restrict__ emb8f, unsigned char* __restrict__ wgt8f,
        float* __restrict__ TL, float* __restrict__ PU) {
    const int b = blockIdx.x;
    const int tid = threadIdx.x;
    const int w = tid >> 6, l = tid & 63;
    const int sub = w * 4 + (l >> 4);             // row-in-block 0..15
    const int l16 = l & 15;                       // 16 floats per lane

    if (b < 64 + WGTBLK) {                        // --- normalize -> fp8 ---
        const bool isEmb = (b < 64);
        const float* src = isEmb ? emb : wgt;
        unsigned char* dst = isEmb ? emb8f : wgt8f;
        const int r = (isEmb ? b : b - 64) * 16 + sub;
        const int r16 = r & 15;
        float v[16];
        float ss = 0.f;
        const float* rp = src + (size_t)r * DIM + l16 * 16;
#pragma unroll
        for (int i = 0; i < 4; ++i) {
            float4 a = *(const float4*)(rp + i * 4);
            v[i*4+0]=a.x; v[i*4+1]=a.y; v[i*4+2]=a.z; v[i*4+3]=a.w;
            ss += a.x*a.x + a.y*a.y + a.z*a.z + a.w*a.w;
        }
#pragma unroll
        for (int k = 1; k < 16; k <<= 1) ss += __shfl_xor(ss, k);
        // scale by SQK so A.B = 30*log2e*cos  (exp2(acc) needs no shift)
        const float sc = SQK / fmaxf(sqrtf(ss), 1e-12f);
        unsigned char* tb = dst + (size_t)(r >> 4) * 4096;
#pragma unroll
        for (int h = 0; h < 2; ++h) {             // two 8-byte k-groups/lane
            const int g = 2 * l16 + h;            // k = 8g..8g+7
            const int s = g >> 2, q = g & 3;
            int p0 = 0, p1 = 0;
            p0 = __builtin_amdgcn_cvt_pk_fp8_f32(v[h*8+0]*sc, v[h*8+1]*sc, p0, false);
            p0 = __builtin_amdgcn_cvt_pk_fp8_f32(v[h*8+2]*sc, v[h*8+3]*sc, p0, true);
            p1 = __builtin_amdgcn_cvt_pk_fp8_f32(v[h*8+4]*sc, v[h*8+5]*sc, p1, false);
            p1 = __builtin_amdgcn_cvt_pk_fp8_f32(v[h*8+6]*sc, v[h*8+7]*sc, p1, true);
            uint2 o; o.x = (unsigned)p0; o.y = (unsigned)p1;
            *(uint2*)(tb + (s >> 1) * 1024 + (r16 + 16 * q) * 16 + (s & 1) * 8) = o;
        }
    } else {                                      // --- target row pass ---
        const int r = (b - 64 - WGTBLK) * 16 + sub;
        const int lbl = labels[r];
        const float* ep = emb + (size_t)r * DIM + l16 * 16;
        const float* wp = wgt + (size_t)lbl * DIM + l16 * 16;
        float de = 0.f, dw = 0.f, dd = 0.f;
#pragma unroll
        for (int i = 0; i < 4; ++i) {
            float4 a = *(const float4*)(ep + i * 4);
            float4 bq = *(const float4*)(wp + i * 4);
            de += a.x*a.x + a.y*a.y + a.z*a.z + a.w*a.w;
            dw += bq.x*bq.x + bq.y*bq.y + bq.z*bq.z + bq.w*bq.w;
            dd += a.x*bq.x + a.y*bq.y + a.z*bq.z + a.w*bq.w;
        }
#pragma unroll
        for (int k = 1; k < 16; k <<= 1) {
            de += __shfl_xor(de, k); dw += __shfl_xor(dw, k); dd += __shfl_xor(dd, k);
        }
        if (l16 == 0) {
            float t = dd / (fmaxf(sqrtf(de), 1e-12f) * fmaxf(sqrtf(dw), 1e-12f));
            t = fminf(fmaxf(t, -CLIPV), CLIPV);
            PU[r] = exp2f(t * K30L2E);            // unadjusted p, unshifted
            TL[r] = t * COSM - sqrtf(fmaxf(1.f - t * t, 0.f)) * SINM;
        }
    }
}

// ---------------- k_main: fused GEMM + register softmax partials ----------
__global__ __launch_bounds__(256, 6) void k_main(
        const unsigned char* __restrict__ wgt8f,
        const unsigned char* __restrict__ emb8f,
        float* __restrict__ SP, unsigned* __restrict__ MP) {
    const int cg = blockIdx.x;            // class group 0..249
    const int rg = blockIdx.y;            // row group 0..7
    const int tid = threadIdx.x;
    const int w = tid >> 6, l = tid & 63;
    const int r16 = l & 15, q = l >> 4;
    const int rowbase = rg * 128 + w * 32;   // wave's 32 rows (2 M-tiles)

    // A-fragments held in registers the whole kernel (fragment layout)
    long af[2][8];
#pragma unroll
    for (int mt = 0; mt < 2; ++mt) {
        const ulong2v* ap =
            (const ulong2v*)(emb8f + (size_t)((rowbase >> 4) + mt) * 4096) + l;
#pragma unroll
        for (int p = 0; p < 4; ++p) {
            ulong2v v = ap[p * 64];
            af[mt][2*p]   = (long)v.x;
            af[mt][2*p+1] = (long)v.y;
        }
    }

    float sum[2][4] = {{0.f,0.f,0.f,0.f},{0.f,0.f,0.f,0.f}};
    float mx [2][4] = {{0.f,0.f,0.f,0.f},{0.f,0.f,0.f,0.f}};  // max of p

    const ulong2v* bp = (const ulong2v*)(wgt8f + (size_t)(cg * TPG) * 4096) + l;
    for (int t = 0; t < TPG; ++t, bp += 256) {
        long bf[8];
#pragma unroll
        for (int p = 0; p < 4; ++p) {             // 4 x 1KB coalesced
            ulong2v v = bp[p * 64];
            bf[2*p]   = (long)v.x;
            bf[2*p+1] = (long)v.y;
        }
#pragma unroll
        for (int mt = 0; mt < 2; ++mt) {
            floatx4 acc = {0.f, 0.f, 0.f, 0.f};
#pragma unroll
            for (int s = 0; s < 8; ++s)
                acc = __builtin_amdgcn_mfma_f32_16x16x32_fp8_fp8(af[mt][s], bf[s], acc, 0, 0, 0);
            // acc = 30*log2e*cos (scale folded into fp8): 3 ops/logit.
#pragma unroll
            for (int r = 0; r < 4; ++r) {
                const float p = exp2f(acc[r]);
                sum[mt][r] += p;
                mx[mt][r] = fmaxf(mx[mt][r], p);
            }
        }
    }

    // one butterfly per wave (over the 16 class-columns)
#pragma unroll
    for (int k = 1; k < 16; k <<= 1)
#pragma unroll
        for (int mt = 0; mt < 2; ++mt)
#pragma unroll
            for (int r = 0; r < 4; ++r) {
                sum[mt][r] += __shfl_xor(sum[mt][r], k);
                mx[mt][r] = fmaxf(mx[mt][r], __shfl_xor(mx[mt][r], k));
            }
    if (r16 < 4) {
#pragma unroll
        for (int mt = 0; mt < 2; ++mt) {
            float sv = sum[mt][0], mv = mx[mt][0];
            if (r16 == 1) { sv = sum[mt][1]; mv = mx[mt][1]; }
            else if (r16 == 2) { sv = sum[mt][2]; mv = mx[mt][2]; }
            else if (r16 == 3) { sv = sum[mt][3]; mv = mx[mt][3]; }
            const int row = rowbase + mt * 16 + q * 4 + r16;
            SP[cg * BATCH + row] = sv;
            MP[cg * BATCH + row] = __float_as_uint(mv);
        }
    }
}

// ---------------- k_final: reduce partials + loss/acc + mean -------------
__global__ __launch_bounds__(256) void k_final(
        const float* __restrict__ SP, const unsigned* __restrict__ MP,
        const float* __restrict__ TL, const float* __restrict__ PU,
        float* __restrict__ out) {
    __shared__ float    ls[16][16];
    __shared__ unsigned lm[16][16];
    const int tid = threadIdx.x;
    const int r16 = tid & 15;                 // row within block
    const int c   = tid >> 4;                 // partial-chunk lane
    const int row = blockIdx.x * 16 + r16;
    float s = 0.f;
    unsigned m = 0u;
    for (int b = c; b < NCT; b += 16) {       // 64B-coalesced row groups
        s += SP[(size_t)b * BATCH + row];
        const unsigned v = MP[(size_t)b * BATCH + row];
        m = v > m ? v : m;
    }
    ls[c][r16] = s; lm[c][r16] = m;
    __syncthreads();
    float loss = 0.f, corr = 0.f;
    if (tid < 16) {
        float st = 0.f; unsigned mt = 0u;
#pragma unroll
        for (int i = 0; i < 16; ++i) {
            st += ls[i][tid];
            mt = lm[i][tid] > mt ? lm[i][tid] : mt;
        }
        const int r = blockIdx.x * 16 + tid;
        const float tl = TL[r];
        const float padj = exp2f(tl * K30L2E);
        st = st - PU[r] + padj;               // swap target p: unadj -> adj
        loss = logf(st) - 30.f * tl;          // logsumexp - target logit
        corr = (padj >= __uint_as_float(mt)) ? 1.f : 0.f;
    }
#pragma unroll
    for (int k = 1; k < 16; k <<= 1) {        // lanes 16..63 carry zeros
        loss += __shfl_xor(loss, k);
        corr += __shfl_xor(corr, k);
    }
    if (tid == 0) {
        atomicAdd(out + 0, loss * (1.f / 1024.f));
        atomicAdd(out + 1, corr * (1.f / 1024.f));
    }
}

extern "C" void kernel_launch(void* const* d_in, const int* in_sizes, int n_in,
                              void* d_out, int out_size, void* d_ws, size_t ws_size,
                              hipStream_t stream) {
    (void)in_sizes; (void)n_in; (void)out_size; (void)ws_size;
    const float* emb    = (const float*)d_in[0];
    const float* wgt    = (const float*)d_in[1];
    const int*   labels = (const int*)d_in[2];
    char* ws = (char*)d_ws;
    unsigned char* emb8f = (unsigned char*)(ws + EMBF_OFF);
    unsigned char* wgt8f = (unsigned char*)(ws + WGTF_OFF);
    float*    TL = (float*)(ws + TL_OFF);
    float*    PU = (float*)(ws + PU_OFF);
    float*    SP = (float*)(ws + SP_OFF);
    unsigned* MP = (unsigned*)(ws + MP_OFF);

    hipMemsetAsync(d_out, 0, 2 * sizeof(float), stream);  // k_final accumulates
    k_prep<<<64 + WGTBLK + 64, 256, 0, stream>>>(emb, wgt, labels,
                                                 emb8f, wgt8f, TL, PU);
    k_main<<<dim3(NCT, RG), 256, 0, stream>>>(wgt8f, emb8f, SP, MP);
    k_final<<<64, 256, 0, stream>>>(SP, MP, TL, PU, (float*)d_out);
}